// Round 3
// baseline (136.601 us; speedup 1.0000x reference)
//
#include <hip/hip_runtime.h>
#include <cmath>

// DotMaskLayer: B=16384, D=256, H=64, M=128.
// keep(j) = (j < K) | (128 <= j < 128+K)  [j=256 bias only if K>128; K<=128 in data]
// out[b,h] = tanh( sum_j keep(j)*Y[b,j]*W[b,j,h] ),  W = AUX.reshape(B,257,64)
// NOTE: block-2 term is X[128+j'] * W[128+j', h]  (X indexed at the SAME j).
//
// One wave per batch row. Lane l: row-offset jo=l>>4, h-quad h4=(l&15)*4.
// Fused j-ranges (identical trip counts) + 2x unroll -> 4 independent 1KB
// wave-loads in flight per iteration to cover HBM latency.

#define D_DIM 256
#define H_DIM 64
#define ROWS 257
#define ROWSTRIDE (ROWS * H_DIM)   // 16448 floats per batch row of AUX

__global__ __launch_bounds__(256, 8)
void dotmask_kernel(const float* __restrict__ X,
                    const float* __restrict__ AUX,
                    const int* __restrict__ K,
                    float* __restrict__ out,
                    int B)
{
    const int lane = threadIdx.x & 63;
    const int wid  = threadIdx.x >> 6;          // wave within block (0..3)
    const int b    = blockIdx.x * 4 + wid;      // one wave per batch row
    if (b >= B) return;

    const int k = K[b];
    const float* __restrict__ Wb = AUX + (size_t)b * ROWSTRIDE;
    const float* __restrict__ Xb = X   + (size_t)b * D_DIM;

    const int jo = lane >> 4;          // row offset within 4-row group (0..3)
    const int h4 = (lane & 15) * 4;    // this lane's 4 consecutive h's

    float ax = 0.f, ay = 0.f, az = 0.f, aw = 0.f;

    // Fused + 2x-unrolled loop over j0 in [0,k) step 8.
    // Rows: ja, ja+128, jb, jb+128 with ja=j0+jo<=127, jb=ja+4<=127 when k<=128
    // (last iter ja/jb may exceed k: masked via zeroed X multiplier; loads stay
    //  in-bounds since max row index is 255 < 257).
    for (int j0 = 0; j0 < k; j0 += 8) {
        const int ja = j0 + jo;
        const int jb = ja + 4;

        // issue all 4 W loads up front (independent 1KB wave-loads)
        const float4 wa1 = *reinterpret_cast<const float4*>(Wb + (size_t)ja         * H_DIM + h4);
        const float4 wa2 = *reinterpret_cast<const float4*>(Wb + (size_t)(ja + 128) * H_DIM + h4);
        const float4 wb1 = *reinterpret_cast<const float4*>(Wb + (size_t)jb         * H_DIM + h4);
        const float4 wb2 = *reinterpret_cast<const float4*>(Wb + (size_t)(jb + 128) * H_DIM + h4);

        const float xa1r = Xb[ja];
        const float xa2r = Xb[ja + 128];
        const float xb1r = Xb[jb & 127];         // jb<=127 normally; & keeps in-bounds
        const float xb2r = Xb[(jb & 127) + 128];

        const bool ka = (ja < k);
        const bool kb = (jb < k);
        const float xa1 = ka ? xa1r : 0.f;
        const float xa2 = ka ? xa2r : 0.f;
        const float xb1 = kb ? xb1r : 0.f;
        const float xb2 = kb ? xb2r : 0.f;

        ax += xa1 * wa1.x; ay += xa1 * wa1.y; az += xa1 * wa1.z; aw += xa1 * wa1.w;
        ax += xa2 * wa2.x; ay += xa2 * wa2.y; az += xa2 * wa2.z; aw += xa2 * wa2.w;
        ax += xb1 * wb1.x; ay += xb1 * wb1.y; az += xb1 * wb1.z; aw += xb1 * wb1.w;
        ax += xb2 * wb2.x; ay += xb2 * wb2.y; az += xb2 * wb2.z; aw += xb2 * wb2.w;
    }

    // bias row j=256 (kept only if k > 128; Y=1). K<=128 in this dataset.
    if (k > 128 && jo == 0) {
        const float4 w = *reinterpret_cast<const float4*>(Wb + (size_t)256 * H_DIM + h4);
        ax += w.x; ay += w.y; az += w.z; aw += w.w;
    }

    // reduce across the 4 jo-groups (lanes l, l+16, l+32, l+48 share h4)
    ax += __shfl_xor(ax, 16); ay += __shfl_xor(ay, 16);
    az += __shfl_xor(az, 16); aw += __shfl_xor(aw, 16);
    ax += __shfl_xor(ax, 32); ay += __shfl_xor(ay, 32);
    az += __shfl_xor(az, 32); aw += __shfl_xor(aw, 32);

    if (lane < 16) {
        float4 r;
        r.x = tanhf(ax); r.y = tanhf(ay); r.z = tanhf(az); r.w = tanhf(aw);
        *reinterpret_cast<float4*>(out + (size_t)b * H_DIM + h4) = r;
    }
}

extern "C" void kernel_launch(void* const* d_in, const int* in_sizes, int n_in,
                              void* d_out, int out_size, void* d_ws, size_t ws_size,
                              hipStream_t stream)
{
    const float* X   = (const float*)d_in[0];
    const float* AUX = (const float*)d_in[1];
    const int*   K   = (const int*)d_in[2];
    float* out = (float*)d_out;

    const int B = in_sizes[2];                 // 16384
    const int blocks = (B + 3) / 4;            // 4 waves (rows) per 256-thread block
    dotmask_kernel<<<blocks, 256, 0, stream>>>(X, AUX, K, out, B);
}

// Round 4
// 116.189 us; speedup vs baseline: 1.1757x; 1.1757x over previous
//
#include <hip/hip_runtime.h>
#include <cmath>

// DotMaskLayer: B=16384, D=256, H=64, M=128.
// keep(j) = (j < K) | (128 <= j < 128+K)  [j=256 bias iff K>128; K<=128 in data]
// out[b,h] = tanh( sum_j keep(j)*Y[b,j]*W[b,j,h] ),  W = AUX.reshape(B,257,64)
// Y[b,j] = X[b,j] for j<256, Y[b,256] = 1.
//
// One 256-thread block per batch row b (split-K): the 4 waves divide the
// j-range [0,k) into 4-row chunks round-robin (wave w owns chunks w, w+4, ...),
// each chunk also covering the mirrored rows [128+j0, 128+j0+4). This makes
// intra-block work uniform (+-1 chunk), so block runtime ~ K[b] and greedy
// block scheduling is work-conserving -- fixing the E[max4 K] ~ 1.6x slot
// inflation of the 4-independent-rows-per-block layout.
//
// Lane layout within a wave: jo = lane>>4 (row in chunk), h4 = (lane&15)*4
// -> each W row-group load is 64 lanes x 16B = 1KB contiguous.

#define D_DIM 256
#define H_DIM 64
#define ROWS 257
#define ROWSTRIDE (ROWS * H_DIM)   // 16448 floats per batch row of AUX

__global__ __launch_bounds__(256, 8)
void dotmask_kernel(const float* __restrict__ X,
                    const float* __restrict__ AUX,
                    const int* __restrict__ K,
                    float* __restrict__ out)
{
    const int b    = blockIdx.x;
    const int tid  = threadIdx.x;
    const int lane = tid & 63;
    const int w    = tid >> 6;          // wave id 0..3 (all share this b)

    const int k = K[b];
    const float* __restrict__ Wb = AUX + (size_t)b * ROWSTRIDE;
    const float* __restrict__ Xb = X   + (size_t)b * D_DIM;

    const int jo = lane >> 4;           // row offset within 4-row chunk
    const int h4 = (lane & 15) * 4;     // this lane's 4 consecutive h's

    float ax = 0.f, ay = 0.f, az = 0.f, aw = 0.f;

    // Wave w owns 4-row chunks starting at j0 = 4*(w + 4t).
    for (int j0 = w * 4; j0 < k; j0 += 16) {
        const int j  = j0 + jo;                 // <= k+2 <= 130  (in-bounds, row < 257)
        const int j2 = j + 128;                 // <= 258 -> clamp for load safety
        const int j2c = (j2 > 256) ? 256 : j2;  // clamped lanes are mask-zeroed anyway

        const float4 w1 = *reinterpret_cast<const float4*>(Wb + (size_t)j   * H_DIM + h4);
        const float4 w2 = *reinterpret_cast<const float4*>(Wb + (size_t)j2c * H_DIM + h4);
        const float x1r = Xb[j];                          // j <= 130 < 256
        const float x2r = Xb[(j2c > 255) ? 255 : j2c];    // clamp; masked if clamped

        const bool  m  = (j < k);
        const float x1 = m ? x1r : 0.f;
        const float x2 = m ? x2r : 0.f;

        ax += x1 * w1.x; ay += x1 * w1.y; az += x1 * w1.z; aw += x1 * w1.w;
        ax += x2 * w2.x; ay += x2 * w2.y; az += x2 * w2.z; aw += x2 * w2.w;
    }

    // bias row j=256 (kept iff k > 128; never with this data, kept for generality)
    if (k > 128 && w == 0 && jo == 0) {
        const float4 wv = *reinterpret_cast<const float4*>(Wb + (size_t)256 * H_DIM + h4);
        ax += wv.x; ay += wv.y; az += wv.z; aw += wv.w;
    }

    // reduce across the 4 jo-groups within the wave (lanes sharing h4)
    ax += __shfl_xor(ax, 16); ay += __shfl_xor(ay, 16);
    az += __shfl_xor(az, 16); aw += __shfl_xor(aw, 16);
    ax += __shfl_xor(ax, 32); ay += __shfl_xor(ay, 32);
    az += __shfl_xor(az, 32); aw += __shfl_xor(aw, 32);

    // combine the 4 waves' partials via LDS
    __shared__ float lds[4][H_DIM];
    if (lane < 16) {
        float4 p; p.x = ax; p.y = ay; p.z = az; p.w = aw;
        *reinterpret_cast<float4*>(&lds[w][h4]) = p;
    }
    __syncthreads();

    if (tid < H_DIM) {
        const float s = lds[0][tid] + lds[1][tid] + lds[2][tid] + lds[3][tid];
        out[(size_t)b * H_DIM + tid] = tanhf(s);
    }
}

extern "C" void kernel_launch(void* const* d_in, const int* in_sizes, int n_in,
                              void* d_out, int out_size, void* d_ws, size_t ws_size,
                              hipStream_t stream)
{
    const float* X   = (const float*)d_in[0];
    const float* AUX = (const float*)d_in[1];
    const int*   K   = (const int*)d_in[2];
    float* out = (float*)d_out;

    const int B = in_sizes[2];                 // 16384
    dotmask_kernel<<<B, 256, 0, stream>>>(X, AUX, K, out);
}